// Round 1
// baseline (1766.149 us; speedup 1.0000x reference)
//
#include <hip/hip_runtime.h>

// Problem constants (from reference setup)
#define NB    128          // batches
#define NA    29           // atoms per batch
#define FD    64           // feature dim
#define NK    64           // radial basis size
#define NEDGE 812          // NA*(NA-1)
#define NEF   (NB*NEDGE)   // 103936 total edges
#define NITERS 2

// ---------------------------------------------------------------------------
// Kernel 1: per-edge radial basis -> rproj[it][e][f] = sum_k radial[e][k] * mp_basis_w[it][k][f]
// Wave-per-edge; W columns in VGPRs; radial transposed through per-wave LDS.
// ---------------------------------------------------------------------------
__global__ __launch_bounds__(256) void edge_rproj_kernel(
    const float* __restrict__ pos,      // [NB*NA][3]
    const float* __restrict__ Wb,       // [NITERS][NK][FD]
    float* __restrict__ rproj)          // [NITERS][NEF][FD]
{
  __shared__ float rads[4][NK];
  const int lane = threadIdx.x & 63;
  const int wv   = threadIdx.x >> 6;

  // W columns for this lane's f, both iterations (128 VGPRs)
  float w0r[64], w1r[64];
  #pragma unroll
  for (int k = 0; k < 64; ++k) {
    w0r[k] = Wb[k*FD + lane];
    w1r[k] = Wb[NK*FD + k*FD + lane];
  }
  const float kk   = (float)lane;
  const float logc = lgammaf(64.0f) - lgammaf(kk + 1.0f) - lgammaf(64.0f - kk);

  for (int e0 = blockIdx.x * 4; e0 < NEF; e0 += gridDim.x * 4) {
    const int e  = e0 + wv;                  // NEF % 4 == 0, always valid
    const int bb = e / NEDGE;
    const int le = e - bb*NEDGE;
    const int i  = le / 28;
    const int jr = le - i*28;
    const int j  = jr + (jr >= i ? 1 : 0);
    const int dn = (bb*NA + i)*3, sn = (bb*NA + j)*3;

    const float dx = pos[sn+0]-pos[dn+0];
    const float dy = pos[sn+1]-pos[dn+1];
    const float dz = pos[sn+2]-pos[dn+2];
    const float r  = sqrtf(dx*dx + dy*dy + dz*dz + 1e-12f);
    const float u    = 1.0f/(1.0f + r);
    const float lu   = logf(u);
    const float l1mu = logf(fmaxf(1.0f - u, 1e-12f));
    const float x2   = (r*0.2f)*(r*0.2f);
    const float fcut = (x2 < 1.0f) ? expf(1.0f - 1.0f/fmaxf(1.0f - x2, 1e-12f)) : 0.0f;

    const float rad = expf(logc + kk*lu + (63.0f - kk)*l1mu) * fcut;
    rads[wv][lane] = rad;
    // same-wave LDS write->read: ds ops execute in order per wave; compiler
    // inserts lgkmcnt (may-alias). No cross-wave sharing -> no barrier.
    float a0 = 0.0f, a1 = 0.0f;
    #pragma unroll
    for (int k4 = 0; k4 < 16; ++k4) {
      const float4 rv = *(const float4*)&rads[wv][k4*4];
      a0 += w0r[k4*4+0]*rv.x; a0 += w0r[k4*4+1]*rv.y;
      a0 += w0r[k4*4+2]*rv.z; a0 += w0r[k4*4+3]*rv.w;
      a1 += w1r[k4*4+0]*rv.x; a1 += w1r[k4*4+1]*rv.y;
      a1 += w1r[k4*4+2]*rv.z; a1 += w1r[k4*4+3]*rv.w;
    }
    const size_t eo = (size_t)e*FD + lane;
    rproj[eo] = a0;
    rproj[(size_t)NEF*FD + eo] = a1;
  }
}

// ---------------------------------------------------------------------------
// Generic 20-path Clebsch-Gordan tensor product at one feature index.
// a[pc], bb[pc], o[pc] with pc = parity*4 + channel (0=l0, 1..3=l1 xyz).
// ---------------------------------------------------------------------------
__device__ __forceinline__ void tp20(const float* a, const float* bb,
                                     const float* w, float* o)
{
  #pragma unroll
  for (int p1 = 0; p1 < 2; ++p1) {
    #pragma unroll
    for (int p2 = 0; p2 < 2; ++p2) {
      const float* w5 = w + 5*(2*p1 + p2);
      const float s1 = a[p1*4+0], x1 = a[p1*4+1], y1 = a[p1*4+2], z1 = a[p1*4+3];
      const float s2 = bb[p2*4+0], x2 = bb[p2*4+1], y2 = bb[p2*4+2], z2 = bb[p2*4+3];
      const int so = (p1 == p2) ? 0 : 4;   // dest parity for T1..T4
      const int vo = 4 - so;               // dest parity for T5 (cross)
      o[so+0] += w5[0]*(s1*s2) + w5[3]*(x1*x2 + y1*y2 + z1*z2);
      o[so+1] += w5[1]*(s1*x2) + w5[2]*(x1*s2);
      o[so+2] += w5[1]*(s1*y2) + w5[2]*(y1*s2);
      o[so+3] += w5[1]*(s1*z2) + w5[2]*(z1*s2);
      o[vo+1] += w5[4]*(y1*z2 - z1*y2);
      o[vo+2] += w5[4]*(z1*x2 - x1*z2);
      o[vo+3] += w5[4]*(x1*y2 - y1*x2);
    }
  }
}

// ---------------------------------------------------------------------------
// Parity-blocked dense: r[t][p*4+c] = sum_f in[n][p*4+c][f] * W[p][sel(c)][f][g] (+bias on c==0)
// Thread (a8,g) handles atoms n = a8+8t. W column kept in 64 VGPRs per sel.
// ---------------------------------------------------------------------------
__device__ __forceinline__ void dense29(const float (*in)[8][FD],
                                        const float* __restrict__ W,
                                        const float* __restrict__ bias,
                                        int a8, int g, float r[4][8])
{
  #pragma unroll
  for (int p = 0; p < 2; ++p) {
    float wc[64];
    // ---- sel 0 (scalar channel)
    #pragma unroll
    for (int f = 0; f < 64; ++f) wc[f] = W[((p*2+0)*64 + f)*64 + g];
    const float bsv = bias ? bias[p*64 + g] : 0.0f;
    #pragma unroll
    for (int t = 0; t < 4; ++t) {
      const int n = a8 + 8*t;
      if (n >= NA) continue;
      float acc = bsv;
      #pragma unroll
      for (int f4 = 0; f4 < 16; ++f4) {
        const float4 xv = *(const float4*)&in[n][p*4+0][f4*4];
        acc += wc[f4*4+0]*xv.x; acc += wc[f4*4+1]*xv.y;
        acc += wc[f4*4+2]*xv.z; acc += wc[f4*4+3]*xv.w;
      }
      r[t][p*4+0] = acc;
    }
    // ---- sel 1 (vector channels)
    #pragma unroll
    for (int f = 0; f < 64; ++f) wc[f] = W[((p*2+1)*64 + f)*64 + g];
    #pragma unroll
    for (int t = 0; t < 4; ++t) {
      const int n = a8 + 8*t;
      if (n >= NA) continue;
      float a1 = 0.0f, a2 = 0.0f, a3 = 0.0f;
      #pragma unroll
      for (int f4 = 0; f4 < 16; ++f4) {
        const float4 xa = *(const float4*)&in[n][p*4+1][f4*4];
        const float4 xb = *(const float4*)&in[n][p*4+2][f4*4];
        const float4 xc = *(const float4*)&in[n][p*4+3][f4*4];
        a1 += wc[f4*4+0]*xa.x; a1 += wc[f4*4+1]*xa.y; a1 += wc[f4*4+2]*xa.z; a1 += wc[f4*4+3]*xa.w;
        a2 += wc[f4*4+0]*xb.x; a2 += wc[f4*4+1]*xb.y; a2 += wc[f4*4+2]*xb.z; a2 += wc[f4*4+3]*xb.w;
        a3 += wc[f4*4+0]*xc.x; a3 += wc[f4*4+1]*xc.y; a3 += wc[f4*4+2]*xc.z; a3 += wc[f4*4+3]*xc.w;
      }
      r[t][p*4+1] = a1; r[t][p*4+2] = a2; r[t][p*4+3] = a3;
    }
  }
}

// ---------------------------------------------------------------------------
// Kernel 2: whole model for one batch per block. 512 threads = 8 waves.
// Thread (a8 = tid>>6, g = tid&63) owns feature-column g of atoms {a8+8t}.
// ---------------------------------------------------------------------------
__global__ __launch_bounds__(512, 2) void fused_model_kernel(
    const int*   __restrict__ Z,        // [NB*NA]
    const float* __restrict__ pos,      // [NB*NA][3]
    const float* __restrict__ Ef,       // [NB][3]
    const float* __restrict__ embed,    // [MAXZ][FD]
    const float* __restrict__ mp_tp_w,  // [NITERS][20][FD]
    const float* __restrict__ d1w,      // [NITERS][2][2][FD][FD]
    const float* __restrict__ d1b,      // [NITERS][2][FD]
    const float* __restrict__ d2w,
    const float* __restrict__ d2b,
    const float* __restrict__ tens_w,   // [NITERS][20][FD]
    const float* __restrict__ tdw,      // [NITERS][2][2][FD][FD]
    const float* __restrict__ td_tp_w,  // [NITERS][20][FD]
    const float* __restrict__ out_w,    // [FD]
    const float* __restrict__ ebias,    // [MAXZ]
    const float* __restrict__ rproj,    // [NITERS][NEF][FD]
    float* __restrict__ out)            // [NB]
{
  __shared__ float xs[NA][8][FD];     // node state x           (59392 B)
  __shared__ float ts[NA][8][FD];     // dense intermediate     (59392 B)
  __shared__ float us[NEDGE][3];      // unit vectors           ( 9744 B)
  __shared__ float posb[NA][3];
  __shared__ int   zsh[NA];
  __shared__ float red[8];

  const int b   = blockIdx.x;
  const int tid = threadIdx.x;
  const int a8  = tid >> 6;
  const int g   = tid & 63;

  if (tid < NA) {
    zsh[tid]     = Z[b*NA + tid];
    posb[tid][0] = pos[(b*NA + tid)*3 + 0];
    posb[tid][1] = pos[(b*NA + tid)*3 + 1];
    posb[tid][2] = pos[(b*NA + tid)*3 + 2];
  }
  const float efx = Ef[b*3+0], efy = Ef[b*3+1], efz = Ef[b*3+2];
  __syncthreads();

  // init x: scalar-regular = embed[Z], rest 0
  #pragma unroll
  for (int t = 0; t < 4; ++t) {
    const int n = a8 + 8*t;
    if (n < NA) {
      xs[n][0][g] = embed[zsh[n]*FD + g];
      #pragma unroll
      for (int pc = 1; pc < 8; ++pc) xs[n][pc][g] = 0.0f;
    }
  }
  // unit vectors for all 812 (dst=i, src=j) pairs: disp = pos[j]-pos[i]
  for (int le = tid; le < NEDGE; le += 512) {
    const int i  = le / 28;
    const int jr = le - i*28;
    const int j  = jr + (jr >= i ? 1 : 0);
    const float dx = posb[j][0] - posb[i][0];
    const float dy = posb[j][1] - posb[i][1];
    const float dz = posb[j][2] - posb[i][2];
    const float ri = 1.0f / sqrtf(dx*dx + dy*dy + dz*dz + 1e-12f);
    us[le][0] = dx*ri; us[le][1] = dy*ri; us[le][2] = dz*ri;
  }
  __syncthreads();

  float ya[4][8];

  for (int it = 0; it < NITERS; ++it) {
    // ================= P1: message aggregation: y[n] = sum_j msg(x[j] -> n)
    const float* wmv = mp_tp_w + it*20*FD;
    float wm[10];
    #pragma unroll
    for (int q = 0; q < 5; ++q) { wm[q] = wmv[q*FD + g]; wm[5+q] = wmv[(10+q)*FD + g]; }
    #pragma unroll
    for (int t = 0; t < 4; ++t)
      #pragma unroll
      for (int pc = 0; pc < 8; ++pc) ya[t][pc] = 0.0f;

    const float* rpb  = rproj + (size_t)it*NEF*FD + (size_t)b*NEDGE*FD;
    const bool   last = (it == NITERS-1);

    for (int j = 0; j < NA; ++j) {
      const float s1  = xs[j][0][g], v1x = xs[j][1][g], v1y = xs[j][2][g], v1z = xs[j][3][g];
      const float s1p = xs[j][4][g], q1x = xs[j][5][g], q1y = xs[j][6][g], q1z = xs[j][7][g];
      #pragma unroll
      for (int t = 0; t < 4; ++t) {
        const int n = a8 + 8*t;
        if (n >= NA || n == j) continue;
        const int le = n*28 + (j < n ? j : j-1);
        const float ux = us[le][0], uy = us[le][1], uz = us[le][2];
        const float rp = rpb[(size_t)le*FD + g];
        const float dot1 = v1x*ux + v1y*uy + v1z*uz;
        const float dotp = q1x*ux + q1y*uy + q1z*uz;
        ya[t][0] += rp*(wm[0]*s1  + wm[3]*dot1);
        ya[t][4] += rp*(wm[5]*s1p + wm[8]*dotp);
        if (!last) {
          const float c1x = v1y*uz - v1z*uy, c1y = v1z*ux - v1x*uz, c1z = v1x*uy - v1y*ux;
          const float cpx = q1y*uz - q1z*uy, cpy = q1z*ux - q1x*uz, cpz = q1x*uy - q1y*ux;
          const float aa = wm[1]*s1, bbp = wm[6]*s1p;
          ya[t][1] += rp*(aa*ux + wm[2]*v1x + wm[9]*cpx);
          ya[t][2] += rp*(aa*uy + wm[2]*v1y + wm[9]*cpy);
          ya[t][3] += rp*(aa*uz + wm[2]*v1z + wm[9]*cpz);
          ya[t][5] += rp*(bbp*ux + wm[7]*q1x + wm[4]*c1x);
          ya[t][6] += rp*(bbp*uy + wm[7]*q1y + wm[4]*c1y);
          ya[t][7] += rp*(bbp*uz + wm[7]*q1z + wm[4]*c1z);
        }
      }
    }
    __syncthreads();               // all reads of xs done before updates

    // x1 = x + y (register y; wave-local rows)
    #pragma unroll
    for (int t = 0; t < 4; ++t) {
      const int n = a8 + 8*t;
      if (n < NA) {
        #pragma unroll
        for (int pc = 0; pc < 8; ++pc) xs[n][pc][g] += ya[t][pc];
      }
    }

    // ================= P2: h = silu(d1(x1)) -> ts   (all wave-local rows)
    {
      float hr[4][8];
      dense29(xs, d1w + it*4*64*64, d1b + it*2*64, a8, g, hr);
      #pragma unroll
      for (int t = 0; t < 4; ++t) {
        const int n = a8 + 8*t;
        if (n >= NA) continue;
        #pragma unroll
        for (int p = 0; p < 2; ++p) {
          const float sv = hr[t][p*4];
          const float sg = 1.0f / (1.0f + expf(-sv));
          ts[n][p*4+0][g] = sv*sg;
          ts[n][p*4+1][g] = hr[t][p*4+1]*sg;
          ts[n][p*4+2][g] = hr[t][p*4+2]*sg;
          ts[n][p*4+3][g] = hr[t][p*4+3]*sg;
        }
      }
    }

    // ================= P3: x2 = d2(h)+y ; x3 = x2 + tp(x2, xEF, tens_w) -> xs (+regs)
    float x3r[4][8];
    {
      float h2[4][8];
      dense29(ts, d2w + it*4*64*64, d2b + it*2*64, a8, g, h2);
      float w20[20];
      #pragma unroll
      for (int q = 0; q < 20; ++q) w20[q] = tens_w[(it*20+q)*FD + g];
      const float bbv[8] = {1.0f, efx, efy, efz, 1.0f, efx, efy, efz};
      #pragma unroll
      for (int t = 0; t < 4; ++t) {
        const int n = a8 + 8*t;
        if (n >= NA) continue;
        float x2v[8], o[8];
        #pragma unroll
        for (int pc = 0; pc < 8; ++pc) { x2v[pc] = h2[t][pc] + ya[t][pc]; o[pc] = 0.0f; }
        tp20(x2v, bbv, w20, o);
        #pragma unroll
        for (int pc = 0; pc < 8; ++pc) {
          const float v = x2v[pc] + o[pc];
          x3r[t][pc] = v;
          xs[n][pc][g] = v;
        }
      }
    }

    // ================= P4+P5: td = dense(x3, tdw); x4 = tp(x3, td, td_tp_w) -> xs
    {
      float td[4][8];
      dense29(xs, tdw + it*4*64*64, nullptr, a8, g, td);
      float w20[20];
      #pragma unroll
      for (int q = 0; q < 20; ++q) w20[q] = td_tp_w[(it*20+q)*FD + g];
      #pragma unroll
      for (int t = 0; t < 4; ++t) {
        const int n = a8 + 8*t;
        if (n >= NA) continue;
        float o[8];
        #pragma unroll
        for (int pc = 0; pc < 8; ++pc) o[pc] = 0.0f;
        tp20(x3r[t], td[t], w20, o);
        #pragma unroll
        for (int pc = 0; pc < 8; ++pc) xs[n][pc][g] = o[pc];
      }
    }
    __syncthreads();               // xs consistent for next iteration / output
  }

  // ================= energy: sum_n ( x[n,0,0,:] . out_w + ebias[Z[n]] )
  const float owg = out_w[g];
  float part = 0.0f;
  #pragma unroll
  for (int t = 0; t < 4; ++t) {
    const int n = a8 + 8*t;
    if (n < NA) part += xs[n][0][g] * owg;
  }
  #pragma unroll
  for (int off = 32; off > 0; off >>= 1) part += __shfl_xor(part, off, 64);
  if (g == 0) red[a8] = part;
  __syncthreads();
  if (tid == 0) {
    float s = 0.0f;
    #pragma unroll
    for (int q = 0; q < 8; ++q) s += red[q];
    float be = 0.0f;
    for (int n = 0; n < NA; ++n) be += ebias[zsh[n]];
    out[b] = s + be;
  }
}

// ---------------------------------------------------------------------------
extern "C" void kernel_launch(void* const* d_in, const int* in_sizes, int n_in,
                              void* d_out, int out_size, void* d_ws, size_t ws_size,
                              hipStream_t stream)
{
  (void)in_sizes; (void)n_in; (void)out_size; (void)ws_size;
  const int*   Z     = (const int*)  d_in[0];
  const float* pos   = (const float*)d_in[1];
  const float* Ef    = (const float*)d_in[2];
  // d_in[3]/d_in[4] (dst_idx/src_idx) are the full i!=j meshgrid; structure is
  // reproduced analytically in-kernel.
  const float* embed = (const float*)d_in[5];
  const float* mpbw  = (const float*)d_in[6];
  const float* mptpw = (const float*)d_in[7];
  const float* d1w   = (const float*)d_in[8];
  const float* d1b   = (const float*)d_in[9];
  const float* d2w   = (const float*)d_in[10];
  const float* d2b   = (const float*)d_in[11];
  const float* tensw = (const float*)d_in[12];
  const float* tdw   = (const float*)d_in[13];
  const float* tdtpw = (const float*)d_in[14];
  const float* outw  = (const float*)d_in[15];
  const float* ebias = (const float*)d_in[16];

  float* rproj = (float*)d_ws;   // needs 2*NEF*64*4 = 53,215,232 B

  edge_rproj_kernel<<<1024, 256, 0, stream>>>(pos, mpbw, rproj);
  fused_model_kernel<<<NB, 512, 0, stream>>>(Z, pos, Ef, embed, mptpw,
      d1w, d1b, d2w, d2b, tensw, tdw, tdtpw, outw, ebias, rproj,
      (float*)d_out);
}

// Round 2
// 311.636 us; speedup vs baseline: 5.6673x; 5.6673x over previous
//
#include <hip/hip_runtime.h>

// Problem constants (from reference setup)
#define NB    128          // batches
#define NA    29           // atoms per batch
#define FD    64           // feature dim
#define NK    64           // radial basis size
#define NEDGE 812          // NA*(NA-1)
#define NEF   (NB*NEDGE)   // 103936 total edges
#define NITERS 2

// ---------------------------------------------------------------------------
// Kernel 1: per-edge radial basis -> rproj[it][e][f] = sum_k radial[e][k] * mp_basis_w[it][k][f]
// Wave-per-edge; W columns in VGPRs; radial transposed through per-wave LDS.
// ---------------------------------------------------------------------------
__global__ __launch_bounds__(256) void edge_rproj_kernel(
    const float* __restrict__ pos,      // [NB*NA][3]
    const float* __restrict__ Wb,       // [NITERS][NK][FD]
    float* __restrict__ rproj)          // [NITERS][NEF][FD]
{
  __shared__ float rads[4][NK];
  const int lane = threadIdx.x & 63;
  const int wv   = threadIdx.x >> 6;

  // W columns for this lane's f, both iterations (128 VGPRs)
  float w0r[64], w1r[64];
  #pragma unroll
  for (int k = 0; k < 64; ++k) {
    w0r[k] = Wb[k*FD + lane];
    w1r[k] = Wb[NK*FD + k*FD + lane];
  }
  const float kk   = (float)lane;
  const float logc = lgammaf(64.0f) - lgammaf(kk + 1.0f) - lgammaf(64.0f - kk);

  for (int e0 = blockIdx.x * 4; e0 < NEF; e0 += gridDim.x * 4) {
    const int e  = e0 + wv;                  // NEF % 4 == 0, always valid
    const int bb = e / NEDGE;
    const int le = e - bb*NEDGE;
    const int i  = le / 28;
    const int jr = le - i*28;
    const int j  = jr + (jr >= i ? 1 : 0);
    const int dn = (bb*NA + i)*3, sn = (bb*NA + j)*3;

    const float dx = pos[sn+0]-pos[dn+0];
    const float dy = pos[sn+1]-pos[dn+1];
    const float dz = pos[sn+2]-pos[dn+2];
    const float r  = sqrtf(dx*dx + dy*dy + dz*dz + 1e-12f);
    const float u    = 1.0f/(1.0f + r);
    const float lu   = logf(u);
    const float l1mu = logf(fmaxf(1.0f - u, 1e-12f));
    const float x2   = (r*0.2f)*(r*0.2f);
    const float fcut = (x2 < 1.0f) ? expf(1.0f - 1.0f/fmaxf(1.0f - x2, 1e-12f)) : 0.0f;

    const float rad = expf(logc + kk*lu + (63.0f - kk)*l1mu) * fcut;
    rads[wv][lane] = rad;
    // same-wave LDS write->read: ds ops execute in order per wave; compiler
    // inserts lgkmcnt (may-alias). No cross-wave sharing -> no barrier.
    float a0 = 0.0f, a1 = 0.0f;
    #pragma unroll
    for (int k4 = 0; k4 < 16; ++k4) {
      const float4 rv = *(const float4*)&rads[wv][k4*4];
      a0 += w0r[k4*4+0]*rv.x; a0 += w0r[k4*4+1]*rv.y;
      a0 += w0r[k4*4+2]*rv.z; a0 += w0r[k4*4+3]*rv.w;
      a1 += w1r[k4*4+0]*rv.x; a1 += w1r[k4*4+1]*rv.y;
      a1 += w1r[k4*4+2]*rv.z; a1 += w1r[k4*4+3]*rv.w;
    }
    const size_t eo = (size_t)e*FD + lane;
    rproj[eo] = a0;
    rproj[(size_t)NEF*FD + eo] = a1;
  }
}

// ---------------------------------------------------------------------------
// Generic 20-path Clebsch-Gordan tensor product at one feature index.
// a[pc], bb[pc], o[pc] with pc = parity*4 + channel (0=l0, 1..3=l1 xyz).
// ---------------------------------------------------------------------------
__device__ __forceinline__ void tp20(const float* a, const float* bb,
                                     const float* w, float* o)
{
  #pragma unroll
  for (int p1 = 0; p1 < 2; ++p1) {
    #pragma unroll
    for (int p2 = 0; p2 < 2; ++p2) {
      const float* w5 = w + 5*(2*p1 + p2);
      const float s1 = a[p1*4+0], x1 = a[p1*4+1], y1 = a[p1*4+2], z1 = a[p1*4+3];
      const float s2 = bb[p2*4+0], x2 = bb[p2*4+1], y2 = bb[p2*4+2], z2 = bb[p2*4+3];
      const int so = (p1 == p2) ? 0 : 4;   // dest parity for T1..T4
      const int vo = 4 - so;               // dest parity for T5 (cross)
      o[so+0] += w5[0]*(s1*s2) + w5[3]*(x1*x2 + y1*y2 + z1*z2);
      o[so+1] += w5[1]*(s1*x2) + w5[2]*(x1*s2);
      o[so+2] += w5[1]*(s1*y2) + w5[2]*(y1*s2);
      o[so+3] += w5[1]*(s1*z2) + w5[2]*(z1*s2);
      o[vo+1] += w5[4]*(y1*z2 - z1*y2);
      o[vo+2] += w5[4]*(z1*x2 - x1*z2);
      o[vo+3] += w5[4]*(x1*y2 - y1*x2);
    }
  }
}

// ---------------------------------------------------------------------------
// Parity-blocked dense, f-outer formulation (NO 64-wide register array ->
// no spills under a 256-VGPR budget). Thread (a8,g) computes output feature
// g for atom rows n = a8 + 8t. Weight loads are per-lane-coalesced global
// reads (stride-64 floats), L1/L2 resident; each is reused for 4 atom rows.
// LDS reads are wave-broadcast (same address across lanes) -> conflict-free.
// ---------------------------------------------------------------------------
__device__ __forceinline__ void dense29(const float (*in)[8][FD],
                                        const float* __restrict__ W,
                                        const float* __restrict__ bias,
                                        int a8, int g, float r[4][8])
{
  #pragma unroll
  for (int p = 0; p < 2; ++p) {
    // ---- sel 0 (scalar channel)
    {
      const float bsv = bias ? bias[p*64 + g] : 0.0f;
      float acc[4] = {bsv, bsv, bsv, bsv};
      const float* Wp = W + (p*2+0)*64*64 + g;
      #pragma unroll
      for (int f4 = 0; f4 < 16; ++f4) {
        const float w0 = Wp[(f4*4+0)*64];
        const float w1 = Wp[(f4*4+1)*64];
        const float w2 = Wp[(f4*4+2)*64];
        const float w3 = Wp[(f4*4+3)*64];
        #pragma unroll
        for (int t = 0; t < 4; ++t) {
          const int n = a8 + 8*t;
          if (n >= NA) continue;
          const float4 xv = *(const float4*)&in[n][p*4+0][f4*4];
          acc[t] += w0*xv.x + w1*xv.y + w2*xv.z + w3*xv.w;
        }
      }
      #pragma unroll
      for (int t = 0; t < 4; ++t) r[t][p*4+0] = acc[t];
    }
    // ---- sel 1 (vector channels, 3 components share weights)
    {
      float a1[4] = {0,0,0,0}, a2[4] = {0,0,0,0}, a3[4] = {0,0,0,0};
      const float* Wp = W + (p*2+1)*64*64 + g;
      #pragma unroll
      for (int f4 = 0; f4 < 16; ++f4) {
        const float w0 = Wp[(f4*4+0)*64];
        const float w1 = Wp[(f4*4+1)*64];
        const float w2 = Wp[(f4*4+2)*64];
        const float w3 = Wp[(f4*4+3)*64];
        #pragma unroll
        for (int t = 0; t < 4; ++t) {
          const int n = a8 + 8*t;
          if (n >= NA) continue;
          const float4 xa = *(const float4*)&in[n][p*4+1][f4*4];
          const float4 xb = *(const float4*)&in[n][p*4+2][f4*4];
          const float4 xc = *(const float4*)&in[n][p*4+3][f4*4];
          a1[t] += w0*xa.x + w1*xa.y + w2*xa.z + w3*xa.w;
          a2[t] += w0*xb.x + w1*xb.y + w2*xb.z + w3*xb.w;
          a3[t] += w0*xc.x + w1*xc.y + w2*xc.z + w3*xc.w;
        }
      }
      #pragma unroll
      for (int t = 0; t < 4; ++t) {
        r[t][p*4+1] = a1[t]; r[t][p*4+2] = a2[t]; r[t][p*4+3] = a3[t];
      }
    }
  }
}

// ---------------------------------------------------------------------------
// Kernel 2: whole model for one batch per block. 512 threads = 8 waves.
// Thread (a8 = tid>>6, g = tid&63) owns feature-column g of atoms {a8+8t}.
// __launch_bounds__(512) (one arg only): 8-wave block => compiler caps at
// 256 VGPR. (512,2) was interpreted as min-2-BLOCKS/CU by this toolchain ->
// 128-VGPR cap -> massive scratch spill (1.8 GB HBM writes in round 1).
// ---------------------------------------------------------------------------
__global__ __launch_bounds__(512) void fused_model_kernel(
    const int*   __restrict__ Z,        // [NB*NA]
    const float* __restrict__ pos,      // [NB*NA][3]
    const float* __restrict__ Ef,       // [NB][3]
    const float* __restrict__ embed,    // [MAXZ][FD]
    const float* __restrict__ mp_tp_w,  // [NITERS][20][FD]
    const float* __restrict__ d1w,      // [NITERS][2][2][FD][FD]
    const float* __restrict__ d1b,      // [NITERS][2][FD]
    const float* __restrict__ d2w,
    const float* __restrict__ d2b,
    const float* __restrict__ tens_w,   // [NITERS][20][FD]
    const float* __restrict__ tdw,      // [NITERS][2][2][FD][FD]
    const float* __restrict__ td_tp_w,  // [NITERS][20][FD]
    const float* __restrict__ out_w,    // [FD]
    const float* __restrict__ ebias,    // [MAXZ]
    const float* __restrict__ rproj,    // [NITERS][NEF][FD]
    float* __restrict__ out)            // [NB]
{
  __shared__ float xs[NA][8][FD];     // node state x           (59392 B)
  __shared__ float ts[NA][8][FD];     // dense intermediate     (59392 B)
  __shared__ float us[NEDGE][3];      // unit vectors           ( 9744 B)
  __shared__ float posb[NA][3];
  __shared__ int   zsh[NA];
  __shared__ float red[8];

  const int b   = blockIdx.x;
  const int tid = threadIdx.x;
  const int a8  = tid >> 6;
  const int g   = tid & 63;

  if (tid < NA) {
    zsh[tid]     = Z[b*NA + tid];
    posb[tid][0] = pos[(b*NA + tid)*3 + 0];
    posb[tid][1] = pos[(b*NA + tid)*3 + 1];
    posb[tid][2] = pos[(b*NA + tid)*3 + 2];
  }
  const float efx = Ef[b*3+0], efy = Ef[b*3+1], efz = Ef[b*3+2];
  __syncthreads();

  // init x: scalar-regular = embed[Z], rest 0
  #pragma unroll
  for (int t = 0; t < 4; ++t) {
    const int n = a8 + 8*t;
    if (n < NA) {
      xs[n][0][g] = embed[zsh[n]*FD + g];
      #pragma unroll
      for (int pc = 1; pc < 8; ++pc) xs[n][pc][g] = 0.0f;
    }
  }
  // unit vectors for all 812 (dst=i, src=j) pairs: disp = pos[j]-pos[i]
  for (int le = tid; le < NEDGE; le += 512) {
    const int i  = le / 28;
    const int jr = le - i*28;
    const int j  = jr + (jr >= i ? 1 : 0);
    const float dx = posb[j][0] - posb[i][0];
    const float dy = posb[j][1] - posb[i][1];
    const float dz = posb[j][2] - posb[i][2];
    const float ri = 1.0f / sqrtf(dx*dx + dy*dy + dz*dz + 1e-12f);
    us[le][0] = dx*ri; us[le][1] = dy*ri; us[le][2] = dz*ri;
  }
  __syncthreads();

  float ya[4][8];

  for (int it = 0; it < NITERS; ++it) {
    // ================= P1: message aggregation: y[n] = sum_j msg(x[j] -> n)
    const float* wmv = mp_tp_w + it*20*FD;
    float wm[10];
    #pragma unroll
    for (int q = 0; q < 5; ++q) { wm[q] = wmv[q*FD + g]; wm[5+q] = wmv[(10+q)*FD + g]; }
    #pragma unroll
    for (int t = 0; t < 4; ++t)
      #pragma unroll
      for (int pc = 0; pc < 8; ++pc) ya[t][pc] = 0.0f;

    const float* rpb  = rproj + (size_t)it*NEF*FD + (size_t)b*NEDGE*FD;
    const bool   last = (it == NITERS-1);

    for (int j = 0; j < NA; ++j) {
      const float s1  = xs[j][0][g], v1x = xs[j][1][g], v1y = xs[j][2][g], v1z = xs[j][3][g];
      const float s1p = xs[j][4][g], q1x = xs[j][5][g], q1y = xs[j][6][g], q1z = xs[j][7][g];
      #pragma unroll
      for (int t = 0; t < 4; ++t) {
        const int n = a8 + 8*t;
        if (n >= NA || n == j) continue;
        const int le = n*28 + (j < n ? j : j-1);
        const float ux = us[le][0], uy = us[le][1], uz = us[le][2];
        const float rp = rpb[(size_t)le*FD + g];
        const float dot1 = v1x*ux + v1y*uy + v1z*uz;
        const float dotp = q1x*ux + q1y*uy + q1z*uz;
        ya[t][0] += rp*(wm[0]*s1  + wm[3]*dot1);
        ya[t][4] += rp*(wm[5]*s1p + wm[8]*dotp);
        if (!last) {
          const float c1x = v1y*uz - v1z*uy, c1y = v1z*ux - v1x*uz, c1z = v1x*uy - v1y*ux;
          const float cpx = q1y*uz - q1z*uy, cpy = q1z*ux - q1x*uz, cpz = q1x*uy - q1y*ux;
          const float aa = wm[1]*s1, bbp = wm[6]*s1p;
          ya[t][1] += rp*(aa*ux + wm[2]*v1x + wm[9]*cpx);
          ya[t][2] += rp*(aa*uy + wm[2]*v1y + wm[9]*cpy);
          ya[t][3] += rp*(aa*uz + wm[2]*v1z + wm[9]*cpz);
          ya[t][5] += rp*(bbp*ux + wm[7]*q1x + wm[4]*c1x);
          ya[t][6] += rp*(bbp*uy + wm[7]*q1y + wm[4]*c1y);
          ya[t][7] += rp*(bbp*uz + wm[7]*q1z + wm[4]*c1z);
        }
      }
    }
    __syncthreads();               // all reads of xs done before updates

    // x1 = x + y (register y; wave-local rows)
    #pragma unroll
    for (int t = 0; t < 4; ++t) {
      const int n = a8 + 8*t;
      if (n < NA) {
        #pragma unroll
        for (int pc = 0; pc < 8; ++pc) xs[n][pc][g] += ya[t][pc];
      }
    }

    // ================= P2: h = silu(d1(x1)) -> ts   (all wave-local rows)
    {
      float hr[4][8];
      dense29(xs, d1w + it*4*64*64, d1b + it*2*64, a8, g, hr);
      #pragma unroll
      for (int t = 0; t < 4; ++t) {
        const int n = a8 + 8*t;
        if (n >= NA) continue;
        #pragma unroll
        for (int p = 0; p < 2; ++p) {
          const float sv = hr[t][p*4];
          const float sg = 1.0f / (1.0f + expf(-sv));
          ts[n][p*4+0][g] = sv*sg;
          ts[n][p*4+1][g] = hr[t][p*4+1]*sg;
          ts[n][p*4+2][g] = hr[t][p*4+2]*sg;
          ts[n][p*4+3][g] = hr[t][p*4+3]*sg;
        }
      }
    }

    // ================= P3: x2 = d2(h)+y ; x3 = x2 + tp(x2, xEF, tens_w) -> xs (+regs)
    float x3r[4][8];
    {
      float h2[4][8];
      dense29(ts, d2w + it*4*64*64, d2b + it*2*64, a8, g, h2);
      float w20[20];
      #pragma unroll
      for (int q = 0; q < 20; ++q) w20[q] = tens_w[(it*20+q)*FD + g];
      const float bbv[8] = {1.0f, efx, efy, efz, 1.0f, efx, efy, efz};
      #pragma unroll
      for (int t = 0; t < 4; ++t) {
        const int n = a8 + 8*t;
        if (n >= NA) continue;
        float x2v[8], o[8];
        #pragma unroll
        for (int pc = 0; pc < 8; ++pc) { x2v[pc] = h2[t][pc] + ya[t][pc]; o[pc] = 0.0f; }
        tp20(x2v, bbv, w20, o);
        #pragma unroll
        for (int pc = 0; pc < 8; ++pc) {
          const float v = x2v[pc] + o[pc];
          x3r[t][pc] = v;
          xs[n][pc][g] = v;
        }
      }
    }

    // ================= P4+P5: td = dense(x3, tdw); x4 = tp(x3, td, td_tp_w) -> xs
    {
      float td[4][8];
      dense29(xs, tdw + it*4*64*64, nullptr, a8, g, td);
      float w20[20];
      #pragma unroll
      for (int q = 0; q < 20; ++q) w20[q] = td_tp_w[(it*20+q)*FD + g];
      #pragma unroll
      for (int t = 0; t < 4; ++t) {
        const int n = a8 + 8*t;
        if (n >= NA) continue;
        float o[8];
        #pragma unroll
        for (int pc = 0; pc < 8; ++pc) o[pc] = 0.0f;
        tp20(x3r[t], td[t], w20, o);
        #pragma unroll
        for (int pc = 0; pc < 8; ++pc) xs[n][pc][g] = o[pc];
      }
    }
    __syncthreads();               // xs consistent for next iteration / output
  }

  // ================= energy: sum_n ( x[n,0,0,:] . out_w + ebias[Z[n]] )
  const float owg = out_w[g];
  float part = 0.0f;
  #pragma unroll
  for (int t = 0; t < 4; ++t) {
    const int n = a8 + 8*t;
    if (n < NA) part += xs[n][0][g] * owg;
  }
  #pragma unroll
  for (int off = 32; off > 0; off >>= 1) part += __shfl_xor(part, off, 64);
  if (g == 0) red[a8] = part;
  __syncthreads();
  if (tid == 0) {
    float s = 0.0f;
    #pragma unroll
    for (int q = 0; q < 8; ++q) s += red[q];
    float be = 0.0f;
    for (int n = 0; n < NA; ++n) be += ebias[zsh[n]];
    out[b] = s + be;
  }
}

// ---------------------------------------------------------------------------
extern "C" void kernel_launch(void* const* d_in, const int* in_sizes, int n_in,
                              void* d_out, int out_size, void* d_ws, size_t ws_size,
                              hipStream_t stream)
{
  (void)in_sizes; (void)n_in; (void)out_size; (void)ws_size;
  const int*   Z     = (const int*)  d_in[0];
  const float* pos   = (const float*)d_in[1];
  const float* Ef    = (const float*)d_in[2];
  // d_in[3]/d_in[4] (dst_idx/src_idx) are the full i!=j meshgrid; structure is
  // reproduced analytically in-kernel.
  const float* embed = (const float*)d_in[5];
  const float* mpbw  = (const float*)d_in[6];
  const float* mptpw = (const float*)d_in[7];
  const float* d1w   = (const float*)d_in[8];
  const float* d1b   = (const float*)d_in[9];
  const float* d2w   = (const float*)d_in[10];
  const float* d2b   = (const float*)d_in[11];
  const float* tensw = (const float*)d_in[12];
  const float* tdw   = (const float*)d_in[13];
  const float* tdtpw = (const float*)d_in[14];
  const float* outw  = (const float*)d_in[15];
  const float* ebias = (const float*)d_in[16];

  float* rproj = (float*)d_ws;   // needs 2*NEF*64*4 = 53,215,232 B

  edge_rproj_kernel<<<1024, 256, 0, stream>>>(pos, mpbw, rproj);
  fused_model_kernel<<<NB, 512, 0, stream>>>(Z, pos, Ef, embed, mptpw,
      d1w, d1b, d2w, d2b, tensw, tdw, tdtpw, outw, ebias, rproj,
      (float*)d_out);
}

// Round 3
// 243.167 us; speedup vs baseline: 7.2631x; 1.2816x over previous
//
#include <hip/hip_runtime.h>

// Problem constants (from reference setup)
#define NB    128          // batches
#define NA    29           // atoms per batch
#define FD    64           // feature dim
#define NK    64           // radial basis size
#define NEDGE 812          // NA*(NA-1)
#define NEF   (NB*NEDGE)   // 103936 total edges
#define NITERS 2
#define NWAVE 16           // waves per fused block
#define TPB   1024         // threads per fused block

// ---------------------------------------------------------------------------
// Kernel 1: per-edge radial basis -> rproj[it][e][f] = sum_k radial[e][k] * mp_basis_w[it][k][f]
// Wave-per-edge; W columns in VGPRs; radial transposed through per-wave LDS.
// ---------------------------------------------------------------------------
__global__ __launch_bounds__(256) void edge_rproj_kernel(
    const float* __restrict__ pos,      // [NB*NA][3]
    const float* __restrict__ Wb,       // [NITERS][NK][FD]
    float* __restrict__ rproj)          // [NITERS][NEF][FD]
{
  __shared__ float rads[4][NK];
  const int lane = threadIdx.x & 63;
  const int wv   = threadIdx.x >> 6;

  // W columns for this lane's f, both iterations (128 VGPRs)
  float w0r[64], w1r[64];
  #pragma unroll
  for (int k = 0; k < 64; ++k) {
    w0r[k] = Wb[k*FD + lane];
    w1r[k] = Wb[NK*FD + k*FD + lane];
  }
  const float kk   = (float)lane;
  const float logc = lgammaf(64.0f) - lgammaf(kk + 1.0f) - lgammaf(64.0f - kk);

  for (int e0 = blockIdx.x * 4; e0 < NEF; e0 += gridDim.x * 4) {
    const int e  = e0 + wv;                  // NEF % 4 == 0, always valid
    const int bb = e / NEDGE;
    const int le = e - bb*NEDGE;
    const int i  = le / 28;
    const int jr = le - i*28;
    const int j  = jr + (jr >= i ? 1 : 0);
    const int dn = (bb*NA + i)*3, sn = (bb*NA + j)*3;

    const float dx = pos[sn+0]-pos[dn+0];
    const float dy = pos[sn+1]-pos[dn+1];
    const float dz = pos[sn+2]-pos[dn+2];
    const float r  = sqrtf(dx*dx + dy*dy + dz*dz + 1e-12f);
    const float u    = 1.0f/(1.0f + r);
    const float lu   = logf(u);
    const float l1mu = logf(fmaxf(1.0f - u, 1e-12f));
    const float x2   = (r*0.2f)*(r*0.2f);
    const float fcut = (x2 < 1.0f) ? expf(1.0f - 1.0f/fmaxf(1.0f - x2, 1e-12f)) : 0.0f;

    const float rad = expf(logc + kk*lu + (63.0f - kk)*l1mu) * fcut;
    rads[wv][lane] = rad;
    // same-wave LDS write->read: ds ops execute in order per wave.
    float a0 = 0.0f, a1 = 0.0f;
    #pragma unroll
    for (int k4 = 0; k4 < 16; ++k4) {
      const float4 rv = *(const float4*)&rads[wv][k4*4];
      a0 += w0r[k4*4+0]*rv.x; a0 += w0r[k4*4+1]*rv.y;
      a0 += w0r[k4*4+2]*rv.z; a0 += w0r[k4*4+3]*rv.w;
      a1 += w1r[k4*4+0]*rv.x; a1 += w1r[k4*4+1]*rv.y;
      a1 += w1r[k4*4+2]*rv.z; a1 += w1r[k4*4+3]*rv.w;
    }
    const size_t eo = (size_t)e*FD + lane;
    rproj[eo] = a0;
    rproj[(size_t)NEF*FD + eo] = a1;
  }
}

// ---------------------------------------------------------------------------
// Generic 20-path Clebsch-Gordan tensor product at one feature index.
// a[pc], bb[pc], o[pc] with pc = parity*4 + channel (0=l0, 1..3=l1 xyz).
// ---------------------------------------------------------------------------
__device__ __forceinline__ void tp20(const float* a, const float* bb,
                                     const float* w, float* o)
{
  #pragma unroll
  for (int p1 = 0; p1 < 2; ++p1) {
    #pragma unroll
    for (int p2 = 0; p2 < 2; ++p2) {
      const float* w5 = w + 5*(2*p1 + p2);
      const float s1 = a[p1*4+0], x1 = a[p1*4+1], y1 = a[p1*4+2], z1 = a[p1*4+3];
      const float s2 = bb[p2*4+0], x2 = bb[p2*4+1], y2 = bb[p2*4+2], z2 = bb[p2*4+3];
      const int so = (p1 == p2) ? 0 : 4;   // dest parity for T1..T4
      const int vo = 4 - so;               // dest parity for T5 (cross)
      o[so+0] += w5[0]*(s1*s2) + w5[3]*(x1*x2 + y1*y2 + z1*z2);
      o[so+1] += w5[1]*(s1*x2) + w5[2]*(x1*s2);
      o[so+2] += w5[1]*(s1*y2) + w5[2]*(y1*s2);
      o[so+3] += w5[1]*(s1*z2) + w5[2]*(z1*s2);
      o[vo+1] += w5[4]*(y1*z2 - z1*y2);
      o[vo+2] += w5[4]*(z1*x2 - x1*z2);
      o[vo+3] += w5[4]*(x1*y2 - y1*x2);
    }
  }
}

// ---------------------------------------------------------------------------
// Parity-blocked dense, f-outer formulation (no wide register arrays).
// Thread (a16,g) computes output feature g for atom rows n = a16 + 16t.
// Weight loads are per-lane-coalesced global reads, L2 resident, each
// reused for 2 atom rows. LDS input reads are coalesced, conflict-free.
// ---------------------------------------------------------------------------
__device__ __forceinline__ void dense29(const float (*in)[8][FD],
                                        const float* __restrict__ W,
                                        const float* __restrict__ bias,
                                        int a16, int g, float r[2][8])
{
  #pragma unroll
  for (int p = 0; p < 2; ++p) {
    // ---- sel 0 (scalar channel)
    {
      const float bsv = bias ? bias[p*64 + g] : 0.0f;
      float acc[2] = {bsv, bsv};
      const float* Wp = W + (p*2+0)*64*64 + g;
      #pragma unroll
      for (int f4 = 0; f4 < 16; ++f4) {
        const float w0 = Wp[(f4*4+0)*64];
        const float w1 = Wp[(f4*4+1)*64];
        const float w2 = Wp[(f4*4+2)*64];
        const float w3 = Wp[(f4*4+3)*64];
        #pragma unroll
        for (int t = 0; t < 2; ++t) {
          const int n = a16 + 16*t;
          if (n >= NA) continue;
          const float4 xv = *(const float4*)&in[n][p*4+0][f4*4];
          acc[t] += w0*xv.x + w1*xv.y + w2*xv.z + w3*xv.w;
        }
      }
      #pragma unroll
      for (int t = 0; t < 2; ++t) r[t][p*4+0] = acc[t];
    }
    // ---- sel 1 (vector channels, 3 components share weights)
    {
      float a1[2] = {0,0}, a2[2] = {0,0}, a3[2] = {0,0};
      const float* Wp = W + (p*2+1)*64*64 + g;
      #pragma unroll
      for (int f4 = 0; f4 < 16; ++f4) {
        const float w0 = Wp[(f4*4+0)*64];
        const float w1 = Wp[(f4*4+1)*64];
        const float w2 = Wp[(f4*4+2)*64];
        const float w3 = Wp[(f4*4+3)*64];
        #pragma unroll
        for (int t = 0; t < 2; ++t) {
          const int n = a16 + 16*t;
          if (n >= NA) continue;
          const float4 xa = *(const float4*)&in[n][p*4+1][f4*4];
          const float4 xb = *(const float4*)&in[n][p*4+2][f4*4];
          const float4 xc = *(const float4*)&in[n][p*4+3][f4*4];
          a1[t] += w0*xa.x + w1*xa.y + w2*xa.z + w3*xa.w;
          a2[t] += w0*xb.x + w1*xb.y + w2*xb.z + w3*xb.w;
          a3[t] += w0*xc.x + w1*xc.y + w2*xc.z + w3*xc.w;
        }
      }
      #pragma unroll
      for (int t = 0; t < 2; ++t) {
        r[t][p*4+1] = a1[t]; r[t][p*4+2] = a2[t]; r[t][p*4+3] = a3[t];
      }
    }
  }
}

// ---------------------------------------------------------------------------
// Kernel 2: whole model for one batch per block. 1024 threads = 16 waves
// (4 waves/SIMD -> latency hiding; round-2's 8-wave config was 2/SIMD and
// VALUBusy was only 18.7%). Thread (a16 = tid>>6, g = tid&63) owns feature
// column g of atom rows {a16, a16+16}. VGPR cap at 1024 threads is 128;
// round-2 used 88 with twice the rows/thread, so no spill expected.
// ---------------------------------------------------------------------------
__global__ __launch_bounds__(TPB) void fused_model_kernel(
    const int*   __restrict__ Z,        // [NB*NA]
    const float* __restrict__ pos,      // [NB*NA][3]
    const float* __restrict__ Ef,       // [NB][3]
    const float* __restrict__ embed,    // [MAXZ][FD]
    const float* __restrict__ mp_tp_w,  // [NITERS][20][FD]
    const float* __restrict__ d1w,      // [NITERS][2][2][FD][FD]
    const float* __restrict__ d1b,      // [NITERS][2][FD]
    const float* __restrict__ d2w,
    const float* __restrict__ d2b,
    const float* __restrict__ tens_w,   // [NITERS][20][FD]
    const float* __restrict__ tdw,      // [NITERS][2][2][FD][FD]
    const float* __restrict__ td_tp_w,  // [NITERS][20][FD]
    const float* __restrict__ out_w,    // [FD]
    const float* __restrict__ ebias,    // [MAXZ]
    const float* __restrict__ rproj,    // [NITERS][NEF][FD]
    float* __restrict__ out)            // [NB]
{
  __shared__ float xs[NA][8][FD];     // node state x           (59392 B)
  __shared__ float ts[NA][8][FD];     // dense intermediate     (59392 B)
  __shared__ float us[NEDGE][3];      // unit vectors           ( 9744 B)
  __shared__ float posb[NA][3];
  __shared__ int   zsh[NA];
  __shared__ float red[NWAVE];

  const int b   = blockIdx.x;
  const int tid = threadIdx.x;
  const int a16 = tid >> 6;
  const int g   = tid & 63;

  if (tid < NA) {
    zsh[tid]     = Z[b*NA + tid];
    posb[tid][0] = pos[(b*NA + tid)*3 + 0];
    posb[tid][1] = pos[(b*NA + tid)*3 + 1];
    posb[tid][2] = pos[(b*NA + tid)*3 + 2];
  }
  const float efx = Ef[b*3+0], efy = Ef[b*3+1], efz = Ef[b*3+2];
  __syncthreads();

  // init x: scalar-regular = embed[Z], rest 0
  #pragma unroll
  for (int t = 0; t < 2; ++t) {
    const int n = a16 + 16*t;
    if (n < NA) {
      xs[n][0][g] = embed[zsh[n]*FD + g];
      #pragma unroll
      for (int pc = 1; pc < 8; ++pc) xs[n][pc][g] = 0.0f;
    }
  }
  // unit vectors for all 812 (dst=i, src=j) pairs: disp = pos[j]-pos[i]
  for (int le = tid; le < NEDGE; le += TPB) {
    const int i  = le / 28;
    const int jr = le - i*28;
    const int j  = jr + (jr >= i ? 1 : 0);
    const float dx = posb[j][0] - posb[i][0];
    const float dy = posb[j][1] - posb[i][1];
    const float dz = posb[j][2] - posb[i][2];
    const float ri = 1.0f / sqrtf(dx*dx + dy*dy + dz*dz + 1e-12f);
    us[le][0] = dx*ri; us[le][1] = dy*ri; us[le][2] = dz*ri;
  }
  __syncthreads();

  float ya[2][8];

  for (int it = 0; it < NITERS; ++it) {
    // ================= P1: message aggregation: y[n] = sum_j msg(x[j] -> n)
    const float* wmv = mp_tp_w + it*20*FD;
    float wm[10];
    #pragma unroll
    for (int q = 0; q < 5; ++q) { wm[q] = wmv[q*FD + g]; wm[5+q] = wmv[(10+q)*FD + g]; }
    #pragma unroll
    for (int t = 0; t < 2; ++t)
      #pragma unroll
      for (int pc = 0; pc < 8; ++pc) ya[t][pc] = 0.0f;

    const float* rpb  = rproj + (size_t)it*NEF*FD + (size_t)b*NEDGE*FD;
    const bool   last = (it == NITERS-1);

    for (int j = 0; j < NA; ++j) {
      const float s1  = xs[j][0][g], v1x = xs[j][1][g], v1y = xs[j][2][g], v1z = xs[j][3][g];
      const float s1p = xs[j][4][g], q1x = xs[j][5][g], q1y = xs[j][6][g], q1z = xs[j][7][g];
      #pragma unroll
      for (int t = 0; t < 2; ++t) {
        const int n = a16 + 16*t;
        if (n >= NA || n == j) continue;
        const int le = n*28 + (j < n ? j : j-1);
        const float ux = us[le][0], uy = us[le][1], uz = us[le][2];
        const float rp = rpb[(size_t)le*FD + g];
        const float dot1 = v1x*ux + v1y*uy + v1z*uz;
        const float dotp = q1x*ux + q1y*uy + q1z*uz;
        ya[t][0] += rp*(wm[0]*s1  + wm[3]*dot1);
        ya[t][4] += rp*(wm[5]*s1p + wm[8]*dotp);
        if (!last) {
          const float c1x = v1y*uz - v1z*uy, c1y = v1z*ux - v1x*uz, c1z = v1x*uy - v1y*ux;
          const float cpx = q1y*uz - q1z*uy, cpy = q1z*ux - q1x*uz, cpz = q1x*uy - q1y*ux;
          const float aa = wm[1]*s1, bbp = wm[6]*s1p;
          ya[t][1] += rp*(aa*ux + wm[2]*v1x + wm[9]*cpx);
          ya[t][2] += rp*(aa*uy + wm[2]*v1y + wm[9]*cpy);
          ya[t][3] += rp*(aa*uz + wm[2]*v1z + wm[9]*cpz);
          ya[t][5] += rp*(bbp*ux + wm[7]*q1x + wm[4]*c1x);
          ya[t][6] += rp*(bbp*uy + wm[7]*q1y + wm[4]*c1y);
          ya[t][7] += rp*(bbp*uz + wm[7]*q1z + wm[4]*c1z);
        }
      }
    }
    __syncthreads();               // all reads of xs done before updates

    // x1 = x + y (register y; wave-local rows)
    #pragma unroll
    for (int t = 0; t < 2; ++t) {
      const int n = a16 + 16*t;
      if (n < NA) {
        #pragma unroll
        for (int pc = 0; pc < 8; ++pc) xs[n][pc][g] += ya[t][pc];
      }
    }

    // ================= P2: h = silu(d1(x1)) -> ts   (all wave-local rows)
    {
      float hr[2][8];
      dense29(xs, d1w + it*4*64*64, d1b + it*2*64, a16, g, hr);
      #pragma unroll
      for (int t = 0; t < 2; ++t) {
        const int n = a16 + 16*t;
        if (n >= NA) continue;
        #pragma unroll
        for (int p = 0; p < 2; ++p) {
          const float sv = hr[t][p*4];
          const float sg = 1.0f / (1.0f + expf(-sv));
          ts[n][p*4+0][g] = sv*sg;
          ts[n][p*4+1][g] = hr[t][p*4+1]*sg;
          ts[n][p*4+2][g] = hr[t][p*4+2]*sg;
          ts[n][p*4+3][g] = hr[t][p*4+3]*sg;
        }
      }
    }

    // ================= P3: x2 = d2(h)+y ; x3 = x2 + tp(x2, xEF, tens_w) -> xs (+regs)
    float x3r[2][8];
    {
      float h2[2][8];
      dense29(ts, d2w + it*4*64*64, d2b + it*2*64, a16, g, h2);
      float w20[20];
      #pragma unroll
      for (int q = 0; q < 20; ++q) w20[q] = tens_w[(it*20+q)*FD + g];
      const float bbv[8] = {1.0f, efx, efy, efz, 1.0f, efx, efy, efz};
      #pragma unroll
      for (int t = 0; t < 2; ++t) {
        const int n = a16 + 16*t;
        if (n >= NA) continue;
        float x2v[8], o[8];
        #pragma unroll
        for (int pc = 0; pc < 8; ++pc) { x2v[pc] = h2[t][pc] + ya[t][pc]; o[pc] = 0.0f; }
        tp20(x2v, bbv, w20, o);
        #pragma unroll
        for (int pc = 0; pc < 8; ++pc) {
          const float v = x2v[pc] + o[pc];
          x3r[t][pc] = v;
          xs[n][pc][g] = v;
        }
      }
    }

    // ================= P4+P5: td = dense(x3, tdw); x4 = tp(x3, td, td_tp_w) -> xs
    {
      float td[2][8];
      dense29(xs, tdw + it*4*64*64, nullptr, a16, g, td);
      float w20[20];
      #pragma unroll
      for (int q = 0; q < 20; ++q) w20[q] = td_tp_w[(it*20+q)*FD + g];
      #pragma unroll
      for (int t = 0; t < 2; ++t) {
        const int n = a16 + 16*t;
        if (n >= NA) continue;
        float o[8];
        #pragma unroll
        for (int pc = 0; pc < 8; ++pc) o[pc] = 0.0f;
        tp20(x3r[t], td[t], w20, o);
        #pragma unroll
        for (int pc = 0; pc < 8; ++pc) xs[n][pc][g] = o[pc];
      }
    }
    __syncthreads();               // xs consistent for next iteration / output
  }

  // ================= energy: sum_n ( x[n,0,0,:] . out_w + ebias[Z[n]] )
  const float owg = out_w[g];
  float part = 0.0f;
  #pragma unroll
  for (int t = 0; t < 2; ++t) {
    const int n = a16 + 16*t;
    if (n < NA) part += xs[n][0][g] * owg;
  }
  #pragma unroll
  for (int off = 32; off > 0; off >>= 1) part += __shfl_xor(part, off, 64);
  if (g == 0) red[a16] = part;
  __syncthreads();
  if (tid == 0) {
    float s = 0.0f;
    #pragma unroll
    for (int q = 0; q < NWAVE; ++q) s += red[q];
    float be = 0.0f;
    for (int n = 0; n < NA; ++n) be += ebias[zsh[n]];
    out[b] = s + be;
  }
}

// ---------------------------------------------------------------------------
extern "C" void kernel_launch(void* const* d_in, const int* in_sizes, int n_in,
                              void* d_out, int out_size, void* d_ws, size_t ws_size,
                              hipStream_t stream)
{
  (void)in_sizes; (void)n_in; (void)out_size; (void)ws_size;
  const int*   Z     = (const int*)  d_in[0];
  const float* pos   = (const float*)d_in[1];
  const float* Ef    = (const float*)d_in[2];
  // d_in[3]/d_in[4] (dst_idx/src_idx) are the full i!=j meshgrid; structure is
  // reproduced analytically in-kernel.
  const float* embed = (const float*)d_in[5];
  const float* mpbw  = (const float*)d_in[6];
  const float* mptpw = (const float*)d_in[7];
  const float* d1w   = (const float*)d_in[8];
  const float* d1b   = (const float*)d_in[9];
  const float* d2w   = (const float*)d_in[10];
  const float* d2b   = (const float*)d_in[11];
  const float* tensw = (const float*)d_in[12];
  const float* tdw   = (const float*)d_in[13];
  const float* tdtpw = (const float*)d_in[14];
  const float* outw  = (const float*)d_in[15];
  const float* ebias = (const float*)d_in[16];

  float* rproj = (float*)d_ws;   // needs 2*NEF*64*4 = 53,215,232 B

  edge_rproj_kernel<<<1024, 256, 0, stream>>>(pos, mpbw, rproj);
  fused_model_kernel<<<NB, TPB, 0, stream>>>(Z, pos, Ef, embed, mptpw,
      d1w, d1b, d2w, d2b, tensw, tdw, tdtpw, outw, ebias, rproj,
      (float*)d_out);
}